// Round 1
// baseline (2952.178 us; speedup 1.0000x reference)
//
#include <hip/hip_runtime.h>

// 2-layer LSTM encoder, fused single kernel.
// B=64 blocks (one per sequence), 384 threads:
//   tid 0..255   -> layer-1 gate lanes (gate index = tid; unit j = tid&63, type = tid>>6)
//   tid 256..383 -> layer-2 gate lanes (r = tid-256; unit j = r&31, type = r>>5)
// Layers are software-pipelined: iteration n computes layer1 step n and layer2 step n-1.
// Recurrent weights live in VGPRs (occupancy is irrelevant: 64 blocks on 256 CUs).

#define BATCH 64
#define T 4096
#define IN_DIM 4
#define H1 64
#define H2 32
#define G1 (4 * H1) // 256
#define G2 (4 * H2) // 128
#define NTHREADS (G1 + G2) // 384

__device__ __forceinline__ float sigmoid_fast(float x) {
    float e = __expf(-x);
    return __builtin_amdgcn_rcpf(1.0f + e);
}
__device__ __forceinline__ float tanh_fast(float x) {
    // tanh(x) = 1 - 2/(exp(2x)+1); correct limits at +/-inf via rcp(inf)=0
    float e = __expf(2.0f * x);
    return 1.0f - 2.0f * __builtin_amdgcn_rcpf(e + 1.0f);
}

__global__ __launch_bounds__(NTHREADS, 1)
void lstm2_fused_kernel(const float* __restrict__ x,
                        const float* __restrict__ W_ih1, const float* __restrict__ W_hh1,
                        const float* __restrict__ b_ih1, const float* __restrict__ b_hh1,
                        const float* __restrict__ W_ih2, const float* __restrict__ W_hh2,
                        const float* __restrict__ b_ih2, const float* __restrict__ b_hh2,
                        float* __restrict__ out)
{
    const int b   = blockIdx.x;
    const int tid = threadIdx.x;
    const bool is_l1 = (tid < G1);

    // LDS state
    __shared__ float4 h1s4[2][H1 / 4];  // double-buffered layer1 hidden state
    __shared__ float4 h2s4[H2 / 4];     // layer2 hidden state
    __shared__ float act1[G1];          // activated layer1 gates
    __shared__ float act2[G2];          // activated layer2 gates

    if (tid < H1 / 4) {
        h1s4[0][tid] = make_float4(0.f, 0.f, 0.f, 0.f);
        h1s4[1][tid] = make_float4(0.f, 0.f, 0.f, 0.f);
    } else if (tid < H1 / 4 + H2 / 4) {
        h2s4[tid - H1 / 4] = make_float4(0.f, 0.f, 0.f, 0.f);
    }

    // ---- per-lane weights into registers ----
    float w_rec[H1];   // l1: W_hh1 row ; l2: W_ih2 row
    float w_in1[IN_DIM];
    float w_rec2[H2];  // l2 only: W_hh2 row
    float bias = 0.0f;

    if (is_l1) {
        const int g = tid;
        const float4* wr = (const float4*)(W_hh1 + (size_t)g * H1);
        #pragma unroll
        for (int k4 = 0; k4 < H1 / 4; ++k4) {
            float4 v = wr[k4];
            w_rec[4 * k4 + 0] = v.x; w_rec[4 * k4 + 1] = v.y;
            w_rec[4 * k4 + 2] = v.z; w_rec[4 * k4 + 3] = v.w;
        }
        float4 wi = *(const float4*)(W_ih1 + (size_t)g * IN_DIM);
        w_in1[0] = wi.x; w_in1[1] = wi.y; w_in1[2] = wi.z; w_in1[3] = wi.w;
        bias = b_ih1[g] + b_hh1[g];
    } else {
        const int r = tid - G1;
        const float4* wi = (const float4*)(W_ih2 + (size_t)r * H1);
        #pragma unroll
        for (int k4 = 0; k4 < H1 / 4; ++k4) {
            float4 v = wi[k4];
            w_rec[4 * k4 + 0] = v.x; w_rec[4 * k4 + 1] = v.y;
            w_rec[4 * k4 + 2] = v.z; w_rec[4 * k4 + 3] = v.w;
        }
        const float4* wh = (const float4*)(W_hh2 + (size_t)r * H2);
        #pragma unroll
        for (int k4 = 0; k4 < H2 / 4; ++k4) {
            float4 v = wh[k4];
            w_rec2[4 * k4 + 0] = v.x; w_rec2[4 * k4 + 1] = v.y;
            w_rec2[4 * k4 + 2] = v.z; w_rec2[4 * k4 + 3] = v.w;
        }
        bias = b_ih2[r] + b_hh2[r];
    }

    // cell states (replicated across waves; all replicas see identical LDS inputs)
    float c1 = 0.0f;  // for unit j = tid & 63   (layer1 lanes)
    float c2 = 0.0f;  // for unit j = r  & 31    (layer2 lanes)

    const float4* xptr = (const float4*)(x + (size_t)b * T * IN_DIM); // one float4 per timestep
    float4 xc = is_l1 ? xptr[0] : make_float4(0.f, 0.f, 0.f, 0.f);

    __syncthreads(); // LDS init visible

    for (int n = 0; n <= T; ++n) {
        const int pb = (n + 1) & 1; // buffer holding h1(n-1)

        // ---------------- phase 1: gate pre-activations ----------------
        if (is_l1) {
            if (n < T) {
                float acc = bias;
                acc = fmaf(xc.x, w_in1[0], acc);
                acc = fmaf(xc.y, w_in1[1], acc);
                acc = fmaf(xc.z, w_in1[2], acc);
                acc = fmaf(xc.w, w_in1[3], acc);
                // prefetch next timestep's x early (latency off critical path)
                if (n + 1 < T) xc = xptr[n + 1];
                const float4* hv = &h1s4[pb][0];
                #pragma unroll
                for (int k4 = 0; k4 < H1 / 4; ++k4) {
                    float4 h = hv[k4];
                    acc = fmaf(h.x, w_rec[4 * k4 + 0], acc);
                    acc = fmaf(h.y, w_rec[4 * k4 + 1], acc);
                    acc = fmaf(h.z, w_rec[4 * k4 + 2], acc);
                    acc = fmaf(h.w, w_rec[4 * k4 + 3], acc);
                }
                const int type = tid >> 6; // 0=i 1=f 2=g 3=o
                act1[tid] = (type == 2) ? tanh_fast(acc) : sigmoid_fast(acc);
            }
        } else {
            if (n >= 1) {
                const int r = tid - G1;
                float acc = bias;
                const float4* hv = &h1s4[pb][0]; // h1(n-1)
                #pragma unroll
                for (int k4 = 0; k4 < H1 / 4; ++k4) {
                    float4 h = hv[k4];
                    acc = fmaf(h.x, w_rec[4 * k4 + 0], acc);
                    acc = fmaf(h.y, w_rec[4 * k4 + 1], acc);
                    acc = fmaf(h.z, w_rec[4 * k4 + 2], acc);
                    acc = fmaf(h.w, w_rec[4 * k4 + 3], acc);
                }
                const float4* h2v = &h2s4[0];
                #pragma unroll
                for (int k4 = 0; k4 < H2 / 4; ++k4) {
                    float4 h = h2v[k4];
                    acc = fmaf(h.x, w_rec2[4 * k4 + 0], acc);
                    acc = fmaf(h.y, w_rec2[4 * k4 + 1], acc);
                    acc = fmaf(h.z, w_rec2[4 * k4 + 2], acc);
                    acc = fmaf(h.w, w_rec2[4 * k4 + 3], acc);
                }
                const int type = r >> 5;
                act2[r] = (type == 2) ? tanh_fast(acc) : sigmoid_fast(acc);
            }
        }

        __syncthreads();

        // ---------------- phase 2: state update ----------------
        if (is_l1) {
            if (n < T) {
                const int j = tid & (H1 - 1);
                float ig = act1[j];
                float fg = act1[H1 + j];
                float gg = act1[2 * H1 + j];
                float og = act1[3 * H1 + j];
                c1 = fmaf(fg, c1, ig * gg);
                float h = og * tanh_fast(c1);
                if (tid < H1) ((float*)&h1s4[n & 1][0])[j] = h;
            }
        } else {
            if (n >= 1) {
                const int r = tid - G1;
                const int j = r & (H2 - 1);
                float ig = act2[j];
                float fg = act2[H2 + j];
                float gg = act2[2 * H2 + j];
                float og = act2[3 * H2 + j];
                c2 = fmaf(fg, c2, ig * gg);
                float h = og * tanh_fast(c2);
                if (r < H2) {
                    ((float*)&h2s4[0])[j] = h;
                    out[((size_t)b * T + (n - 1)) * H2 + j] = h;
                }
            }
        }

        __syncthreads();
    }
}

extern "C" void kernel_launch(void* const* d_in, const int* in_sizes, int n_in,
                              void* d_out, int out_size, void* d_ws, size_t ws_size,
                              hipStream_t stream) {
    const float* x     = (const float*)d_in[0];
    const float* W_ih1 = (const float*)d_in[1];
    const float* W_hh1 = (const float*)d_in[2];
    const float* b_ih1 = (const float*)d_in[3];
    const float* b_hh1 = (const float*)d_in[4];
    const float* W_ih2 = (const float*)d_in[5];
    const float* W_hh2 = (const float*)d_in[6];
    const float* b_ih2 = (const float*)d_in[7];
    const float* b_hh2 = (const float*)d_in[8];
    float* out = (float*)d_out;

    lstm2_fused_kernel<<<dim3(BATCH), dim3(NTHREADS), 0, stream>>>(
        x, W_ih1, W_hh1, b_ih1, b_hh1, W_ih2, W_hh2, b_ih2, b_hh2, out);
}

// Round 3
// 2771.044 us; speedup vs baseline: 1.0654x; 1.0654x over previous
//
#include <hip/hip_runtime.h>

// 2-layer LSTM encoder, fused single kernel, v3 (= v2 with 2 bugfixes).
// 64 blocks (one per batch element), 512 threads = 8 waves:
//   waves 0..3 : layer-1. 16 units/wave; lane = 16*type + unit_idx.
//                One gate per lane: 4(x) + 64(h1) FMAs, ILP-4 accumulators.
//   waves 4..7 : layer-2. 8 units/wave; lane = 16*type + 2*unit_idx + half.
//                One gate per LANE PAIR: each half does 48 FMAs (32 of W_ih2,
//                16 of W_hh2), combined with shfl_xor(.,1).
// All 4 gates of a unit live in the same wave -> i,f,g,o gathered with
// intra-wave shuffles; c/h updated redundantly in-register (no barrier, no
// LDS round-trip for gates). ONE __syncthreads per timestep.
// Pipeline: iteration n runs layer-1 step n and layer-2 step n-1; BOTH read
// h1(n-1) (buffer rm1, sealed by the previous barrier) while layer-1 writes
// h1(n) into a different buffer (rcur) — race-free with one barrier.
// BUGFIXES vs v2: (1) layer-2 read h1(n-2) instead of h1(n-1);
//                 (2) layer-2 bias was added by BOTH halves of the lane pair.

#define BATCH 64
#define T 4096
#define IN_DIM 4
#define H1 64
#define H2 32
#define NTHREADS 512

__device__ __forceinline__ float fast_rcp(float v) { return __builtin_amdgcn_rcpf(v); }

__global__ __launch_bounds__(NTHREADS, 1)
void lstm2_fused_v3(const float* __restrict__ x,
                    const float* __restrict__ W_ih1, const float* __restrict__ W_hh1,
                    const float* __restrict__ b_ih1, const float* __restrict__ b_hh1,
                    const float* __restrict__ W_ih2, const float* __restrict__ W_hh2,
                    const float* __restrict__ b_ih2, const float* __restrict__ b_hh2,
                    float* __restrict__ out)
{
    const int b    = blockIdx.x;
    const int tid  = threadIdx.x;
    const int wave = tid >> 6;
    const int lane = tid & 63;
    const bool is_l1 = (wave < 4);
    const int type = lane >> 4;        // 0=i 1=f 2=g 3=o
    const int base = lane & 15;        // index of the type-0 lane of my unit
    const int half = lane & 1;         // layer-2 dot-product half

    __shared__ __align__(16) float h1buf[3][H1];
    __shared__ __align__(16) float h2buf[2][H2];

    if (tid < 3 * H1)              ((float*)h1buf)[tid] = 0.0f;
    else if (tid < 3 * H1 + 2 * H2) ((float*)h2buf)[tid - 3 * H1] = 0.0f;

    // unified activation constants: act = sc_out * rcp(1 + exp(sc_in*x)) + sc_off
    // type!=2 -> sigmoid(x); type==2 -> tanh(x) = 2/(1+exp(-2x)) - 1
    const float sc_in  = (type == 2) ? -2.0f : -1.0f;
    const float sc_out = (type == 2) ?  2.0f :  1.0f;
    const float sc_off = (type == 2) ? -1.0f :  0.0f;

    float w_a[64];   // l1: W_hh1 row (64). l2: W_ih2 half-row (32 used)
    float w_b[16];   // l2: W_hh2 half-row (16). unused by l1
    float w_x[4];    // l1: W_ih1 row. unused by l2
    float bias;
    int   j;         // my unit index
    float c = 0.0f;  // cell state (replicated across the unit's lanes)

    if (is_l1) {
        j = 16 * wave + base;
        const int g = type * H1 + j;
        const float4* wr = (const float4*)(W_hh1 + (size_t)g * H1);
        #pragma unroll
        for (int k = 0; k < 16; ++k) {
            float4 v = wr[k];
            w_a[4 * k + 0] = v.x; w_a[4 * k + 1] = v.y;
            w_a[4 * k + 2] = v.z; w_a[4 * k + 3] = v.w;
        }
        float4 wi = *(const float4*)(W_ih1 + (size_t)g * IN_DIM);
        w_x[0] = wi.x; w_x[1] = wi.y; w_x[2] = wi.z; w_x[3] = wi.w;
        bias = b_ih1[g] + b_hh1[g];
    } else {
        const int r = wave - 4;
        j = 8 * r + (base >> 1);
        const int g = type * H2 + j;
        const float4* wi = (const float4*)(W_ih2 + (size_t)g * H1) + (half << 3);
        #pragma unroll
        for (int k = 0; k < 8; ++k) {
            float4 v = wi[k];
            w_a[4 * k + 0] = v.x; w_a[4 * k + 1] = v.y;
            w_a[4 * k + 2] = v.z; w_a[4 * k + 3] = v.w;
        }
        const float4* wh = (const float4*)(W_hh2 + (size_t)g * H2) + (half << 2);
        #pragma unroll
        for (int k = 0; k < 4; ++k) {
            float4 v = wh[k];
            w_b[4 * k + 0] = v.x; w_b[4 * k + 1] = v.y;
            w_b[4 * k + 2] = v.z; w_b[4 * k + 3] = v.w;
        }
        // BUGFIX (2): only half 0 carries the bias (halves are summed later).
        bias = half ? 0.0f : (b_ih2[g] + b_hh2[g]);
    }

    const float4* xptr = (const float4*)(x + (size_t)b * T * IN_DIM);
    float4 xc = is_l1 ? xptr[0] : make_float4(0.f, 0.f, 0.f, 0.f);
    float* outb = out + (size_t)b * T * H2;

    __syncthreads();

    // rotating h1 buffer indices: rcur = write h1(n); rm1 = h1(n-1)
    // (read by BOTH layers); rm2 = h1(n-2) (unused slot this iteration).
    int rcur = 0, rm1 = 2, rm2 = 1;

    for (int n = 0; n <= T; ++n) {
        if (is_l1) {
            if (n < T) {
                float a0 = bias, a1 = 0.f, a2 = 0.f, a3 = 0.f;
                a0 = fmaf(xc.x, w_x[0], a0);
                a1 = fmaf(xc.y, w_x[1], a1);
                a2 = fmaf(xc.z, w_x[2], a2);
                a3 = fmaf(xc.w, w_x[3], a3);
                if (n + 1 < T) xc = xptr[n + 1];   // prefetch next x
                const float4* hv = (const float4*)h1buf[rm1];
                #pragma unroll
                for (int k = 0; k < 16; ++k) {
                    float4 h = hv[k];
                    a0 = fmaf(h.x, w_a[4 * k + 0], a0);
                    a1 = fmaf(h.y, w_a[4 * k + 1], a1);
                    a2 = fmaf(h.z, w_a[4 * k + 2], a2);
                    a3 = fmaf(h.w, w_a[4 * k + 3], a3);
                }
                float acc = (a0 + a1) + (a2 + a3);
                float act = fmaf(sc_out, fast_rcp(1.0f + __expf(sc_in * acc)), sc_off);
                float gi = __shfl(act, base,      64);
                float gf = __shfl(act, base + 16, 64);
                float gg = __shfl(act, base + 32, 64);
                float go = __shfl(act, base + 48, 64);
                c = fmaf(gf, c, gi * gg);
                float th = 1.0f - 2.0f * fast_rcp(__expf(2.0f * c) + 1.0f);
                float h = go * th;
                if (lane < 16) h1buf[rcur][j] = h;
            }
        } else {
            if (n >= 1) {
                float a0 = bias, a1 = 0.f, a2 = 0.f, a3 = 0.f;
                // BUGFIX (1): layer-2 step n-1 consumes h1(n-1) = h1buf[rm1].
                const float4* hv = (const float4*)h1buf[rm1] + (half << 3);
                #pragma unroll
                for (int k = 0; k < 8; ++k) {
                    float4 h = hv[k];
                    a0 = fmaf(h.x, w_a[4 * k + 0], a0);
                    a1 = fmaf(h.y, w_a[4 * k + 1], a1);
                    a2 = fmaf(h.z, w_a[4 * k + 2], a2);
                    a3 = fmaf(h.w, w_a[4 * k + 3], a3);
                }
                const float4* h2v = (const float4*)h2buf[n & 1] + (half << 2);
                #pragma unroll
                for (int k = 0; k < 4; ++k) {
                    float4 h = h2v[k];
                    a0 = fmaf(h.x, w_b[4 * k + 0], a0);
                    a1 = fmaf(h.y, w_b[4 * k + 1], a1);
                    a2 = fmaf(h.z, w_b[4 * k + 2], a2);
                    a3 = fmaf(h.w, w_b[4 * k + 3], a3);
                }
                float part = (a0 + a1) + (a2 + a3);
                float acc = part + __shfl_xor(part, 1, 64);   // combine lane pair
                float act = fmaf(sc_out, fast_rcp(1.0f + __expf(sc_in * acc)), sc_off);
                float gi = __shfl(act, base,      64);
                float gf = __shfl(act, base + 16, 64);
                float gg = __shfl(act, base + 32, 64);
                float go = __shfl(act, base + 48, 64);
                c = fmaf(gf, c, gi * gg);
                float th = 1.0f - 2.0f * fast_rcp(__expf(2.0f * c) + 1.0f);
                float h = go * th;
                if ((lane & 49) == 0) {            // type==0 && half==0
                    h2buf[(n + 1) & 1][j] = h;
                    outb[(size_t)(n - 1) * H2 + j] = h;
                }
            }
        }
        __syncthreads();
        int t0 = rm2; rm2 = rm1; rm1 = rcur; rcur = t0;
    }
}

extern "C" void kernel_launch(void* const* d_in, const int* in_sizes, int n_in,
                              void* d_out, int out_size, void* d_ws, size_t ws_size,
                              hipStream_t stream) {
    const float* x     = (const float*)d_in[0];
    const float* W_ih1 = (const float*)d_in[1];
    const float* W_hh1 = (const float*)d_in[2];
    const float* b_ih1 = (const float*)d_in[3];
    const float* b_hh1 = (const float*)d_in[4];
    const float* W_ih2 = (const float*)d_in[5];
    const float* W_hh2 = (const float*)d_in[6];
    const float* b_ih2 = (const float*)d_in[7];
    const float* b_hh2 = (const float*)d_in[8];
    float* out = (float*)d_out;

    lstm2_fused_v3<<<dim3(BATCH), dim3(NTHREADS), 0, stream>>>(
        x, W_ih1, W_hh1, b_ih1, b_hh1, W_ih2, W_hh2, b_ih2, b_hh2, out);
}